// Round 11
// baseline (193.559 us; speedup 1.0000x reference)
//
#include <hip/hip_runtime.h>

// TAM fused kernel round 11: R10 (191us) with smaller per-sample footprint to
// raise samples-in-flight per CU. 128-thread blocks (thread-cap 16 blocks/CU),
// LDS trimmed to ~15.1KB (no weight/BN LDS staging -- weights read direct from
// L2 in the phases, BN folded inline; sact overlays dead pool region) ->
// 10 samples resident/CU vs 8. DMA staging (R10 win), NT stores (R6 win),
// plain loads (L3 retention). C=12, T=10, H*W=28, K=3.

#define CC 12
#define TT 10
#define SAMPLE 3360
#define SAMPLE4 840
#define EPSF 1e-5f

typedef float f4 __attribute__((ext_vector_type(4)));

__global__ __launch_bounds__(128) void tam_kernel(
    const float* __restrict__ x,
    const float* __restrict__ w_g1,
    const float* __restrict__ g1_gamma, const float* __restrict__ g1_beta,
    const float* __restrict__ g1_mean,  const float* __restrict__ g1_var,
    const float* __restrict__ w_g2,
    const float* __restrict__ w_l1,
    const float* __restrict__ l1_gamma, const float* __restrict__ l1_beta,
    const float* __restrict__ l1_mean,  const float* __restrict__ l1_var,
    const float* __restrict__ w_l2,
    float* __restrict__ out)
{
    __shared__ f4    sx4[SAMPLE4];   // x in input order [c][t][s4]  (13.44 KB)
    __shared__ float spool[120];     // pooled[c][t]; overlaid by sact in ph4
    __shared__ float sz[240];        // G hidden
    __shared__ float sa1[30];        // L hidden [m][t]
    __shared__ float skern[36];      // k0[12] k1[12] k2[12]

    const int n    = blockIdx.x;
    const int tid  = threadIdx.x;    // 0..127
    const int wid  = tid >> 6;       // 0..1
    const int lane = tid & 63;

    // ---- phase 1: stage sample via direct global->LDS DMA ----
    // 13 full-wave chunks of 64 f4 (1KB each) split across the 2 waves.
    const f4* xg = reinterpret_cast<const f4*>(x + (size_t)n * SAMPLE);
    for (int i = wid; i < 13; i += 2) {
        __builtin_amdgcn_global_load_lds(
            (const __attribute__((address_space(1))) void*)(xg + i * 64 + lane),
            (__attribute__((address_space(3))) void*)(&sx4[i * 64]),
            16, 0, 0);
    }
    if (tid < 8) sx4[832 + tid] = xg[832 + tid];   // tail 8 f4
    __syncthreads();

    // ---- phase 2: spatial mean -> spool[c*10+t] (120 threads, 7 f4 each) ----
    if (tid < 120) {
        const f4* rp = sx4 + tid * 7;
        f4 a = rp[0];
        #pragma unroll
        for (int i = 1; i < 7; ++i) a += rp[i];
        spool[tid] = (a.x + a.y + a.z + a.w) * (1.0f / 28.0f);
    }
    __syncthreads();

    // ---- phase 3: G hidden (tasks 0..239) + L conv1 (tasks 240..269) ----
    // Weights read directly from global (L2-hot broadcast); BN folded inline.
    for (int task = tid; task < 270; task += 128) {
        if (task < 240) {
            const int c = task / 20, j = task % 20;
            float s = 0.f;
            #pragma unroll
            for (int t = 0; t < TT; ++t)
                s += spool[c * TT + t] * w_g1[j * TT + t];
            const float rs = rsqrtf(g1_var[j] + EPSF);
            sz[task] = fmaxf((s - g1_mean[j]) * rs * g1_gamma[j] + g1_beta[j], 0.f);
        } else {
            const int e = task - 240;
            const int m = e / TT, t = e % TT;
            float s = 0.f;
            #pragma unroll
            for (int c = 0; c < CC; ++c) {
                #pragma unroll
                for (int k = 0; k < 3; ++k) {
                    const int t2 = t + k - 1;
                    if (t2 >= 0 && t2 < TT)
                        s += spool[c * TT + t2] * w_l1[(m * CC + c) * 3 + k];
                }
            }
            const float rs = rsqrtf(l1_var[m] + EPSF);
            sa1[e] = fmaxf((s - l1_mean[m]) * rs * l1_gamma[m] + l1_beta[m], 0.f);
        }
    }
    __syncthreads();

    // ---- phase 4: L conv2+sigmoid (tid<120) + G softmax (tid 116..127) ----
    // sact overlays spool (pool dead after phase 3).
    float* sact = spool;
    if (tid >= 116) {
        const int c = tid - 116;
        float sc0 = 0.f, sc1 = 0.f, sc2 = 0.f;
        #pragma unroll
        for (int j = 0; j < 20; ++j) {
            const float zj = sz[c * 20 + j];
            sc0 += zj * w_g2[j];
            sc1 += zj * w_g2[20 + j];
            sc2 += zj * w_g2[40 + j];
        }
        const float mx = fmaxf(sc0, fmaxf(sc1, sc2));
        const float e0 = __expf(sc0 - mx), e1 = __expf(sc1 - mx), e2 = __expf(sc2 - mx);
        const float ri = 1.0f / (e0 + e1 + e2);
        skern[c]      = e0 * ri;
        skern[12 + c] = e1 * ri;
        skern[24 + c] = e2 * ri;
    }
    if (tid < 120) {
        const int c = tid / TT, t = tid % TT;
        float s = 0.f;
        #pragma unroll
        for (int m = 0; m < 3; ++m) s += sa1[m * TT + t] * w_l2[c * 3 + m];
        sact[tid] = 1.0f / (1.0f + __expf(-s));
    }
    __syncthreads();

    // ---- phase 5: gated temporal conv, transposed coalesced NT store ----
    // out f4 vo = t*84 + c*7 + s4 ; taps at sx4 f4 = c*70 + t'*7 + s4.
    f4* og = reinterpret_cast<f4*>(out + (size_t)n * SAMPLE);
    #pragma unroll
    for (int k = 0; k < 7; ++k) {
        const int v = tid + k * 128;
        if (k < 6 || tid < 72) {
            const int t   = v / 84;
            const int rem = v % 84;
            const int c   = rem / 7;
            const int s4  = rem % 7;
            const int base = c * 70 + s4;
            const float k0 = skern[c];
            const float k1 = skern[12 + c];
            const float k2 = skern[24 + c];
            f4 acc = (k1 * sact[c * TT + t]) * sx4[base + t * 7];
            if (t > 0)
                acc += (k0 * sact[c * TT + t - 1]) * sx4[base + (t - 1) * 7];
            if (t < TT - 1)
                acc += (k2 * sact[c * TT + t + 1]) * sx4[base + (t + 1) * 7];
            __builtin_nontemporal_store(acc, og + v);
        }
    }
}

extern "C" void kernel_launch(void* const* d_in, const int* in_sizes, int n_in,
                              void* d_out, int out_size, void* d_ws, size_t ws_size,
                              hipStream_t stream) {
    (void)n_in; (void)out_size; (void)d_ws; (void)ws_size;
    const float* x        = (const float*)d_in[0];
    const float* w_g1     = (const float*)d_in[1];
    const float* g1_gamma = (const float*)d_in[2];
    const float* g1_beta  = (const float*)d_in[3];
    const float* g1_mean  = (const float*)d_in[4];
    const float* g1_var   = (const float*)d_in[5];
    const float* w_g2     = (const float*)d_in[6];
    const float* w_l1     = (const float*)d_in[7];
    const float* l1_gamma = (const float*)d_in[8];
    const float* l1_beta  = (const float*)d_in[9];
    const float* l1_mean  = (const float*)d_in[10];
    const float* l1_var   = (const float*)d_in[11];
    const float* w_l2     = (const float*)d_in[12];
    float* out = (float*)d_out;

    const int n_total = in_sizes[0] / SAMPLE;  // 32768
    tam_kernel<<<n_total, 128, 0, stream>>>(
        x, w_g1, g1_gamma, g1_beta, g1_mean, g1_var, w_g2,
        w_l1, l1_gamma, l1_beta, l1_mean, l1_var, w_l2, out);
}